// Round 3
// baseline (432.239 us; speedup 1.0000x reference)
//
#include <hip/hip_runtime.h>

// out[b,c,p] = alpha[slot[b,p], c] * x[b,c,p] + beta[slot[b,p], c]
//   x: [B=32, C=2048, HW=1024] fp32, slot: [B, 1024] int32 in [0,256)
//   alpha/beta: [256, 2048] fp32
//
// Block = (image group of 8, channel group of 8). 256 threads, 1024 blocks
// -> exactly 4 blocks/CU: the ENTIRE grid is co-resident in one round.
// Changes vs R2 (fa ~100 us -> target ~92 us):
//  - IPB 4 -> 8: one staging phase per CU total (was 2 rounds), staging
//    traffic 32 -> 16 MB, zero inter-round tail.
//  - Interleaved float2 table lds_ab[ch][slot] = {alpha, beta}: one
//    ds_read_b64 per (channel, pixel) gather instead of two ds_read_b32 —
//    halves LDS issue slots (LDS pipe ~20% busy; this buys issue headroom,
//    banks still spread by slot).
//  - unroll 2 on the image loop: 2 images of x in flight per wave without
//    blowing the 128-VGPR budget of 4 waves/EU.

typedef float  f4 __attribute__((ext_vector_type(4)));
typedef float  f2 __attribute__((ext_vector_type(2)));
typedef int    i4 __attribute__((ext_vector_type(4)));

#define CH   2048
#define HW   1024
#define NS   256
#define CPB  8              // channels per block
#define NCG  (CH / CPB)     // 256 channel-group blocks
#define IPB  8              // images per block

__global__ __launch_bounds__(256, 4) void fa_kernel(
    const float* __restrict__ x,
    const int*   __restrict__ slot,
    const float* __restrict__ alpha,
    const float* __restrict__ beta,
    float*       __restrict__ out)
{
    __shared__ f2 lds_ab[CPB][NS];   // {alpha, beta} interleaved, 16 KB

    const int cg = blockIdx.x & (NCG - 1);
    const int bg = blockIdx.x >> 8;          // /NCG, in [0,4)
    const int b0 = bg * IPB;
    const int c0 = cg * CPB;
    const int t  = threadIdx.x;
    const int p  = t << 2;

    // ---- staging loads first: the ds_writes wait only on these
    // L2-latency loads (vmcnt in-order), not on the x stream ----
    const f4 ar0 = *(const f4*)(alpha + (size_t)t * CH + c0);
    const f4 ar1 = *(const f4*)(alpha + (size_t)t * CH + c0 + 4);
    const f4 br0 = *(const f4*)(beta  + (size_t)t * CH + c0);
    const f4 br1 = *(const f4*)(beta  + (size_t)t * CH + c0 + 4);

#pragma unroll
    for (int k = 0; k < 4; ++k) {
        lds_ab[k][t]     = (f2){ar0[k], br0[k]};
        lds_ab[4 + k][t] = (f2){ar1[k], br1[k]};
    }

    __syncthreads();

    // ---- stream IPB images through the resident table ----
#pragma unroll 2
    for (int i = 0; i < IPB; ++i) {
        const int b = b0 + i;

        // slot ids for this thread's 4 pixels (coalesced int4, L2-hot)
        const i4 s = *(const i4*)(slot + (size_t)b * HW + p);

        const size_t base = ((size_t)b * CH + c0) * HW + p;
        f4 xv[CPB];
#pragma unroll
        for (int k = 0; k < CPB; ++k)
            xv[k] = __builtin_nontemporal_load((const f4*)(x + base + (size_t)k * HW));

#pragma unroll
        for (int k = 0; k < CPB; ++k) {
            const f2 ab0 = lds_ab[k][s.x];
            const f2 ab1 = lds_ab[k][s.y];
            const f2 ab2 = lds_ab[k][s.z];
            const f2 ab3 = lds_ab[k][s.w];
            f4 o;
            o[0] = ab0[0] * xv[k][0] + ab0[1];
            o[1] = ab1[0] * xv[k][1] + ab1[1];
            o[2] = ab2[0] * xv[k][2] + ab2[1];
            o[3] = ab3[0] * xv[k][3] + ab3[1];
            __builtin_nontemporal_store(o, (f4*)(out + base + (size_t)k * HW));
        }
    }
}

extern "C" void kernel_launch(void* const* d_in, const int* in_sizes, int n_in,
                              void* d_out, int out_size, void* d_ws, size_t ws_size,
                              hipStream_t stream) {
    const float* x     = (const float*)d_in[0];
    const int*   slot  = (const int*)d_in[1];
    const float* alpha = (const float*)d_in[2];
    const float* beta  = (const float*)d_in[3];
    float*       out   = (float*)d_out;

    const int B = in_sizes[0] / (CH * HW);   // 32
    dim3 grid((B / IPB) * NCG);               // 1024 blocks
    dim3 block(256);
    fa_kernel<<<grid, block, 0, stream>>>(x, slot, alpha, beta, out);
}

// Round 5
// 427.188 us; speedup vs baseline: 1.0118x; 1.0118x over previous
//
#include <hip/hip_runtime.h>

// out[b,c,p] = alpha[slot[b,p], c] * x[b,c,p] + beta[slot[b,p], c]
//   x: [B=32, C=2048, HW=1024] fp32, slot: [B, 1024] int32 in [0,256)
//   alpha/beta: [256, 2048] fp32
//
// Block = (image group of 8, channel group of 8). 256 threads, 1024 blocks
// (exactly 4 blocks/CU, whole grid co-resident, one staging phase total).
// R4 resubmit of R3's fix (infra failure last round, kernel untested):
//  - REVERT f2 interleave -> R2's scalar lds[ch][slot] layout. The 8-B f2
//    element mapped slot s to bank-pair (2s)%32 = only 16 positions ->
//    ~4-way random aliasing (2-way is free, 4-way isn't). Scalar b32
//    gathers spread over all 32 banks. (R3 post-mortem: f2 cost ~4 us.)
//  - EXPLICIT 1-image software pipeline, compile-time ping-pong xv[2][8]:
//    slot+x loads of image i+1 are issued BEFORE the stores of image i.
//    vmcnt is in-order, so compute of i+1 then waits at vmcnt(8) with the
//    8 stores of image i still in flight; an implicit unroll-2 schedule
//    risked [stores i][loads i+1] order, whose consume forces vmcnt(0) =
//    a full store-drain stall every image.
//  - Prologue x loads sit between table loads and ds_writes: the barrier's
//    waitcnt is vmcnt(9) (table rows done, x stream in flight) — never a
//    full drain.

typedef float  f4 __attribute__((ext_vector_type(4)));
typedef int    i4 __attribute__((ext_vector_type(4)));

#define CH   2048
#define HW   1024
#define NS   256
#define CPB  8              // channels per block
#define NCG  (CH / CPB)     // 256 channel-group blocks
#define IPB  8              // images per block

__global__ __launch_bounds__(256, 4) void fa_kernel(
    const float* __restrict__ x,
    const int*   __restrict__ slot,
    const float* __restrict__ alpha,
    const float* __restrict__ beta,
    float*       __restrict__ out)
{
    __shared__ float lds_a[CPB][NS];   // 8 KB, gather bank = slot % 32
    __shared__ float lds_b[CPB][NS];   // 8 KB

    const int cg = blockIdx.x & (NCG - 1);
    const int bg = blockIdx.x >> 8;          // /NCG, in [0,4)
    const int b0 = bg * IPB;
    const int c0 = cg * CPB;
    const int t  = threadIdx.x;
    const int p  = t << 2;

    // ---- table staging loads first (L2 latency) ----
    const f4 ar0 = *(const f4*)(alpha + (size_t)t * CH + c0);
    const f4 ar1 = *(const f4*)(alpha + (size_t)t * CH + c0 + 4);
    const f4 br0 = *(const f4*)(beta  + (size_t)t * CH + c0);
    const f4 br1 = *(const f4*)(beta  + (size_t)t * CH + c0 + 4);

    // ---- prologue prefetch for image 0, issued BEFORE the ds_writes so
    // the pre-barrier waitcnt is vmcnt(9), not a full drain ----
    i4 s[2];
    f4 xv[2][CPB];
    s[0] = *(const i4*)(slot + (size_t)b0 * HW + p);
    const size_t base0 = ((size_t)b0 * CH + c0) * HW + p;
#pragma unroll
    for (int k = 0; k < CPB; ++k)
        xv[0][k] = __builtin_nontemporal_load((const f4*)(x + base0 + (size_t)k * HW));

    // transpose table rows into per-channel scalar arrays (stride-1 writes)
#pragma unroll
    for (int k = 0; k < 4; ++k) {
        lds_a[k][t]     = ar0[k];
        lds_a[4 + k][t] = ar1[k];
        lds_b[k][t]     = br0[k];
        lds_b[4 + k][t] = br1[k];
    }

    __syncthreads();

    // ---- explicit software pipeline over IPB images ----
#pragma unroll
    for (int i = 0; i < IPB; ++i) {
        const int cur = i & 1;          // compile-time after full unroll
        const int nxt = cur ^ 1;

        // issue next image's loads FIRST (before this image's stores)
        if (i + 1 < IPB) {
            const int bn = b0 + i + 1;
            s[nxt] = *(const i4*)(slot + (size_t)bn * HW + p);
            const size_t basen = ((size_t)bn * CH + c0) * HW + p;
#pragma unroll
            for (int k = 0; k < CPB; ++k)
                xv[nxt][k] = __builtin_nontemporal_load(
                    (const f4*)(x + basen + (size_t)k * HW));
        }

        const int    b    = b0 + i;
        const size_t base = ((size_t)b * CH + c0) * HW + p;
        const i4     sc   = s[cur];

#pragma unroll
        for (int k = 0; k < CPB; ++k) {
            const float a0 = lds_a[k][sc.x], a1 = lds_a[k][sc.y],
                        a2 = lds_a[k][sc.z], a3 = lds_a[k][sc.w];
            const float q0 = lds_b[k][sc.x], q1 = lds_b[k][sc.y],
                        q2 = lds_b[k][sc.z], q3 = lds_b[k][sc.w];
            f4 o;
            o[0] = a0 * xv[cur][k][0] + q0;
            o[1] = a1 * xv[cur][k][1] + q1;
            o[2] = a2 * xv[cur][k][2] + q2;
            o[3] = a3 * xv[cur][k][3] + q3;
            __builtin_nontemporal_store(o, (f4*)(out + base + (size_t)k * HW));
        }
    }
}

extern "C" void kernel_launch(void* const* d_in, const int* in_sizes, int n_in,
                              void* d_out, int out_size, void* d_ws, size_t ws_size,
                              hipStream_t stream) {
    const float* x     = (const float*)d_in[0];
    const int*   slot  = (const int*)d_in[1];
    const float* alpha = (const float*)d_in[2];
    const float* beta  = (const float*)d_in[3];
    float*       out   = (float*)d_out;

    const int B = in_sizes[0] / (CH * HW);   // 32
    dim3 grid((B / IPB) * NCG);               // 1024 blocks
    dim3 block(256);
    fa_kernel<<<grid, block, 0, stream>>>(x, slot, alpha, beta, out);
}